// Round 5
// baseline (935.842 us; speedup 1.0000x reference)
//
#include <hip/hip_runtime.h>
#include <math.h>

#define T_STEPS 50
#define D_IN    620
#define N1      200
#define N2      100
#define N3      11
#define BATCH   4096

typedef short bf16x8 __attribute__((ext_vector_type(8)));
typedef float f32x4  __attribute__((ext_vector_type(4)));

__device__ __constant__ float KV[10] = {
    -0.0033689735f, -0.0091578194f, -0.0248935342f, -0.0676676416f, -0.1839397206f,
     1.0f,           0.6065306597f,  0.3678794412f,  0.2231301601f,  0.1353352832f };
__device__ __constant__ float KS_TAIL[9] = {
    0.6065306597f, 0.3678794412f, 0.2231301601f, 0.1353352832f, 0.0820849986f,
    0.0497870684f, 0.0301973834f, 0.0183156389f, 0.0111089965f };

__device__ __forceinline__ float sigm10(float x) { return 1.0f / (1.0f + __expf(-10.0f * x)); }
__device__ __forceinline__ float swishf(float v) { return v / (1.0f + __expf(-10.0f * v)); }

__device__ __forceinline__ void split2(float x, unsigned short& hi, unsigned short& lo) {
    unsigned u = __float_as_uint(x);
    hi = (unsigned short)(u >> 16);
    float rem = x - __uint_as_float(u & 0xFFFF0000u);   // exact
    lo = (unsigned short)(__float_as_uint(rem) >> 16);
}

// ---------------------------------------------------------------------------
// Prep W1 -> 20 k-tiles of [p][208 rows][32 bf16], granule^=( (n>>1)&3 ).
// Tile = 13312 ushorts (26624 B) matching gemm1's LDS B image exactly.
// ---------------------------------------------------------------------------
__global__ void prep_w1(const float* __restrict__ W1, unsigned short* __restrict__ W1pre) {
    int i = blockIdx.x * 256 + threadIdx.x;           // 20*2*208*32 = 266240
    if (i >= 266240) return;
    int kk = i & 31;
    int t1 = i >> 5;
    int n  = t1 % 208;
    int t2 = t1 / 208;        // kt*2 + p
    int p  = t2 & 1;
    int kt = t2 >> 1;
    int k  = kt * 32 + kk;
    float w = (n < N1 && k < D_IN) ? W1[n * D_IN + k] : 0.0f;
    unsigned short hi, lo; split2(w, hi, lo);
    int gsw = (kk >> 3) ^ ((n >> 1) & 3);
    int idx = kt * 13312 + p * 6656 + n * 32 + gsw * 8 + (kk & 7);
    W1pre[idx] = p ? lo : hi;
}

// ---------------------------------------------------------------------------
// Prep W2 -> per-wave MFMA B-fragments (unchanged from round 4)
// ---------------------------------------------------------------------------
__global__ void prep_w2(const float* __restrict__ W2, unsigned short* __restrict__ W2pre2) {
    int i = blockIdx.x * 256 + threadIdx.x;
    if (i >= 57344) return;
    int e  = i & 7;
    int r  = i >> 3;
    int l  = r & 63;
    int r2 = r >> 6;
    int p  = r2 & 1;
    int r3 = r2 >> 1;
    int ks = r3 % 7;
    int wv = r3 / 7;
    int n  = wv * 16 + (l & 15);
    int k  = ks * 32 + (l >> 4) * 8 + e;
    float v = (n < N2 && k < N1) ? W2[n * N1 + k] : 0.0f;
    unsigned short hi, lo; split2(v, hi, lo);
    W2pre2[i] = p ? lo : hi;
}

// ---------------------------------------------------------------------------
// MFMA GEMM1 v2: BM=128 (8 waves x 1 M-tile), BN=208, BK=32, 3-pass bf16.
// A: global -> registers (prefetched 1 k-step ahead). B: LDS dbuf 53 KB.
// ---------------------------------------------------------------------------
__global__ __launch_bounds__(512, 4) void gemm1_mfma(const float* __restrict__ x,
                                                     const unsigned short* __restrict__ W1pre,
                                                     float* __restrict__ h1) {
    __shared__ unsigned short Bs[2][13312];           // 53248 B

    const int tid = threadIdx.x;
    const int w   = tid >> 6;
    const int l   = tid & 63;
    const int j   = l >> 4;
    const int r16 = l & 15;
    const long row0 = (long)blockIdx.x * 128;
    const float* arow = x + (row0 + w * 16 + r16) * D_IN;

    f32x4 acc[13];
#pragma unroll
    for (int nt = 0; nt < 13; ++nt) acc[nt] = (f32x4){0.f, 0.f, 0.f, 0.f};

    auto stageB = [&](int kt, int bb) {
        const unsigned short* src = W1pre + kt * 13312;
#pragma unroll
        for (int it = 0; it < 3; ++it) {
            int ch = it * 512 + tid;                  // 16B chunk index
            __builtin_amdgcn_global_load_lds(
                (const __attribute__((address_space(1))) unsigned int*)(src + ch * 8),
                (__attribute__((address_space(3))) unsigned int*)(&Bs[bb][0] + ch * 8), 16, 0, 0);
        }
        if (tid < 128) {
            int ch = 1536 + tid;
            __builtin_amdgcn_global_load_lds(
                (const __attribute__((address_space(1))) unsigned int*)(src + ch * 8),
                (__attribute__((address_space(3))) unsigned int*)(&Bs[bb][0] + ch * 8), 16, 0, 0);
        }
    };

    auto loadA = [&](int kt, float* av) {
        const float* p = arow + kt * 32 + j * 8;
        const float4 u0 = *(const float4*)p;
        const float4 u1 = *(const float4*)(p + 4);
        av[0] = u0.x; av[1] = u0.y; av[2] = u0.z; av[3] = u0.w;
        av[4] = u1.x; av[5] = u1.y; av[6] = u1.z; av[7] = u1.w;
    };
    // kt=19 tail: cols 608..619 valid; never read past row end (no OOB)
    auto loadAtail = [&](float* av) {
        if (j == 0) {
            const float4 u0 = *(const float4*)(arow + 608);
            const float4 u1 = *(const float4*)(arow + 612);
            av[0] = u0.x; av[1] = u0.y; av[2] = u0.z; av[3] = u0.w;
            av[4] = u1.x; av[5] = u1.y; av[6] = u1.z; av[7] = u1.w;
        } else if (j == 1) {
            const float4 u0 = *(const float4*)(arow + 616);
            av[0] = u0.x; av[1] = u0.y; av[2] = u0.z; av[3] = u0.w;
            av[4] = 0.f; av[5] = 0.f; av[6] = 0.f; av[7] = 0.f;
        } else {
#pragma unroll
            for (int e = 0; e < 8; ++e) av[e] = 0.f;
        }
    };

    float avc[8], avn[8];
    stageB(0, 0);
    loadA(0, avc);
    __syncthreads();

    for (int kt = 0; kt < 20; ++kt) {
        const int cur = kt & 1, nxt = cur ^ 1;
        if (kt < 19) {
            stageB(kt + 1, nxt);
            if (kt + 1 == 19) loadAtail(avn); else loadA(kt + 1, avn);
        }
        // split A into hi/lo bf16 fragments
        bf16x8 ah, al;
#pragma unroll
        for (int e = 0; e < 8; ++e) {
            unsigned short hi, lo; split2(avc[e], hi, lo);
            ah[e] = (short)hi; al[e] = (short)lo;
        }
        const unsigned short* B = &Bs[cur][0];
#pragma unroll
        for (int nt = 0; nt < 13; ++nt) {
            const int n  = nt * 16 + r16;
            const int gs = j ^ ((n >> 1) & 3);
            const bf16x8 bh = *(const bf16x8*)(B + n * 32 + gs * 8);
            const bf16x8 bl = *(const bf16x8*)(B + 6656 + n * 32 + gs * 8);
            acc[nt] = __builtin_amdgcn_mfma_f32_16x16x32_bf16(ah, bh, acc[nt], 0, 0, 0);
            acc[nt] = __builtin_amdgcn_mfma_f32_16x16x32_bf16(ah, bl, acc[nt], 0, 0, 0);
            acc[nt] = __builtin_amdgcn_mfma_f32_16x16x32_bf16(al, bh, acc[nt], 0, 0, 0);
        }
        __syncthreads();
#pragma unroll
        for (int e = 0; e < 8; ++e) avc[e] = avn[e];
    }

    // epilogue: D row = w*16 + j*4+q, col = nt*16 + r16
#pragma unroll
    for (int nt = 0; nt < 13; ++nt) {
        const int gcol = nt * 16 + r16;
        if (gcol < N1) {
            const long grow0 = row0 + w * 16 + j * 4;
#pragma unroll
            for (int q = 0; q < 4; ++q)
                h1[(grow0 + q) * N1 + gcol] = swishf(acc[nt][q]);
        }
    }
}

// ---------------------------------------------------------------------------
// In-place causal conv (unchanged)
// ---------------------------------------------------------------------------
__global__ __launch_bounds__(256) void conv_k(float* __restrict__ buf) {
    __shared__ float h1s[T_STEPS * N1];
    const int b = blockIdx.x, tid = threadIdx.x;
    float* p = buf + (size_t)b * (T_STEPS * N1);
    for (int i = tid; i < T_STEPS * N1 / 4; i += 256)
        ((float4*)h1s)[i] = ((const float4*)p)[i];
    __syncthreads();
    for (int i = tid; i < T_STEPS * N1; i += 256) {
        int t = i / N1, n = i - t * N1;
        float s = 0.0f;
#pragma unroll
        for (int k = 0; k < 10; ++k)
            if (k <= t) s = fmaf(KV[k], h1s[(t - k) * N1 + n], s);
        p[i] = s;
    }
}

// ---------------------------------------------------------------------------
// Recurrent scan v3: pipelined. Per step: {P1; bar; MFMA(t) || P345(t-1); bar}
// s2A and h2buf double-buffered; GEMM3+layer4 in owner lanes (within-wave LDS).
// ---------------------------------------------------------------------------
__global__ __launch_bounds__(512, 2) void snn_scan3(const float* __restrict__ syn2,
                                                    const unsigned short* __restrict__ W2pre2,
                                                    const float* __restrict__ W3,
                                                    float* __restrict__ out) {
    __shared__ __align__(16) unsigned short s2A[2][8192];   // 32 KB  [buf][p][16][256]
    __shared__ __align__(16) float h2buf[2][16][132];       // 16.9 KB
    __shared__ __align__(16) float s3buf[16][104];          // 6.7 KB
    __shared__ __align__(16) float W3s[N3 * N2];            // 4.4 KB

    const int tid = threadIdx.x;
    const int g   = tid >> 5;
    const int c   = tid & 31;
    const int wv  = tid >> 6;
    const int l   = tid & 63;
    const int m16 = l & 15;
    const int j2  = l >> 4;
    const long b  = (long)blockIdx.x * 16 + g;

    for (int i = tid; i < N3 * N2; i += 512) W3s[i] = W3[i];
    for (int i = tid; i < 16384; i += 512) ((unsigned short*)s2A)[i] = 0;

    bf16x8 bh[7], bl[7];
    {
        const unsigned short* wp = W2pre2 + wv * 7168 + l * 8;
#pragma unroll
        for (int ks = 0; ks < 7; ++ks) {
            bh[ks] = *(const bf16x8*)(wp + ks * 1024);
            bl[ks] = *(const bf16x8*)(wp + ks * 1024 + 512);
        }
    }

    const int NL2 = (c < 8) ? 7 : 6;
    const int NL3 = (c < 4) ? 4 : 3;

    float sl2h[9][7] = {};
    float h2h[9][4]  = {};
    float sl3h[9][4] = {};
    float h3h[9]     = {};
    float sl4h[9]    = {};
    float accum      = 0.0f;

    const float* syn2b = syn2 + b * (T_STEPS * N1);
    float syn_nxt[7];
#pragma unroll
    for (int jj = 0; jj < 7; ++jj) syn_nxt[jj] = (jj < NL2) ? syn2b[c + 32 * jj] : 0.0f;

    __syncthreads();

    for (int t = 0; t < T_STEPS; ++t) {
        // ---- P1(t): layer-2 update -> s2A[t&1] ----
        float syn_cur[7];
#pragma unroll
        for (int jj = 0; jj < 7; ++jj) syn_cur[jj] = syn_nxt[jj];
        if (t + 1 < T_STEPS) {
#pragma unroll
            for (int jj = 0; jj < 7; ++jj)
                if (jj < NL2) syn_nxt[jj] = syn2b[(t + 1) * N1 + c + 32 * jj];
        }
#pragma unroll
        for (int jj = 0; jj < 7; ++jj) {
            if (jj < NL2) {
                const int n = c + 32 * jj;
                float mem2 = syn_cur[jj];
#pragma unroll
                for (int k = 0; k < 9; ++k) mem2 = fmaf(-KS_TAIL[k], sl2h[k][jj], mem2);
                const float s2  = sigm10(mem2 - 0.5f);
                const float sl2 = s2 * mem2;
#pragma unroll
                for (int k = 8; k > 0; --k) sl2h[k][jj] = sl2h[k - 1][jj];
                sl2h[0][jj] = sl2;
                unsigned short hi, lo; split2(s2, hi, lo);
                const int off = g * 256 + (((n >> 3) ^ (g & 7)) * 8) + (n & 7);
                s2A[t & 1][off]        = hi;
                s2A[t & 1][4096 + off] = lo;
            }
        }
        __syncthreads();                               // bar A

        // ---- P2(t): MFMA GEMM2 (issue first; 2 independent chains) ----
        f32x4 a0 = (f32x4){0.f, 0.f, 0.f, 0.f};
        f32x4 a1 = (f32x4){0.f, 0.f, 0.f, 0.f};
        {
            const unsigned short* S = &s2A[t & 1][0];
            const int swz = m16 & 7;
#pragma unroll
            for (int ks = 0; ks < 7; ++ks) {
                const int gr = (4 * ks + j2) ^ swz;
                const bf16x8 ahv = *(const bf16x8*)&S[m16 * 256 + gr * 8];
                const bf16x8 alv = *(const bf16x8*)&S[4096 + m16 * 256 + gr * 8];
                if (ks & 1) {
                    a1 = __builtin_amdgcn_mfma_f32_16x16x32_bf16(ahv, bh[ks], a1, 0, 0, 0);
                    a1 = __builtin_amdgcn_mfma_f32_16x16x32_bf16(alv, bh[ks], a1, 0, 0, 0);
                    a1 = __builtin_amdgcn_mfma_f32_16x16x32_bf16(ahv, bl[ks], a1, 0, 0, 0);
                } else {
                    a0 = __builtin_amdgcn_mfma_f32_16x16x32_bf16(ahv, bh[ks], a0, 0, 0, 0);
                    a0 = __builtin_amdgcn_mfma_f32_16x16x32_bf16(alv, bh[ks], a0, 0, 0, 0);
                    a0 = __builtin_amdgcn_mfma_f32_16x16x32_bf16(ahv, bl[ks], a0, 0, 0, 0);
                }
            }
        }

        // ---- P345(t-1): VALU work overlapping the MFMA pipe ----
        if (t > 0) {
            const float (*hb)[132] = h2buf[(t + 1) & 1];
#pragma unroll
            for (int jj = 0; jj < 4; ++jj) {
                if (jj < NL3) {
                    const int m = c + 32 * jj;
                    const float hm = hb[g][m];
                    float mem3 = KV[0] * hm;
#pragma unroll
                    for (int k = 0; k < 9; ++k) mem3 = fmaf(KV[k + 1], h2h[k][jj], mem3);
#pragma unroll
                    for (int k = 0; k < 9; ++k) mem3 = fmaf(-KS_TAIL[k], sl3h[k][jj], mem3);
                    const float s3  = sigm10(mem3 - 0.5f);
                    const float sl3 = s3 * mem3;
#pragma unroll
                    for (int k = 8; k > 0; --k) { h2h[k][jj] = h2h[k - 1][jj]; sl3h[k][jj] = sl3h[k - 1][jj]; }
                    h2h[0][jj]  = hm;
                    sl3h[0][jj] = sl3;
                    s3buf[g][m] = s3;
                }
            }
            if (c < N3) {       // GEMM3 + layer 4, owner lanes, within-wave LDS
                float a4 = 0.0f;
#pragma unroll 5
                for (int m = 0; m < N2; m += 4) {
                    const float4 sv  = *(const float4*)&s3buf[g][m];
                    const float4 wv4 = *(const float4*)&W3s[c * N2 + m];
                    a4 = fmaf(sv.x, wv4.x, a4);
                    a4 = fmaf(sv.y, wv4.y, a4);
                    a4 = fmaf(sv.z, wv4.z, a4);
                    a4 = fmaf(sv.w, wv4.w, a4);
                }
                const float h3 = swishf(a4);
                float mem4 = KV[0] * h3;
#pragma unroll
                for (int k = 0; k < 9; ++k) mem4 = fmaf(KV[k + 1], h3h[k], mem4);
#pragma unroll
                for (int k = 0; k < 9; ++k) mem4 = fmaf(-KS_TAIL[k], sl4h[k], mem4);
                const float s4  = sigm10(mem4 - 0.5f);
                const float sl4 = s4 * mem4;
#pragma unroll
                for (int k = 8; k > 0; --k) { h3h[k] = h3h[k - 1]; sl4h[k] = sl4h[k - 1]; }
                h3h[0]  = h3;
                sl4h[0] = sl4;
                accum += s4;
            }
        }

        // ---- P2 epilogue: h2 -> h2buf[t&1] ----
        {
            const f32x4 a = a0 + a1;
#pragma unroll
            for (int q = 0; q < 4; ++q)
                h2buf[t & 1][j2 * 4 + q][wv * 16 + m16] = swishf(a[q]);
        }
        __syncthreads();                               // bar B
    }

    // ---- tail: P345 for t = T_STEPS-1 ----
    {
        const float (*hb)[132] = h2buf[(T_STEPS - 1) & 1];
#pragma unroll
        for (int jj = 0; jj < 4; ++jj) {
            if (jj < NL3) {
                const int m = c + 32 * jj;
                const float hm = hb[g][m];
                float mem3 = KV[0] * hm;
#pragma unroll
                for (int k = 0; k < 9; ++k) mem3 = fmaf(KV[k + 1], h2h[k][jj], mem3);
#pragma unroll
                for (int k = 0; k < 9; ++k) mem3 = fmaf(-KS_TAIL[k], sl3h[k][jj], mem3);
                const float s3 = sigm10(mem3 - 0.5f);
                s3buf[g][m] = s3;
            }
        }
        if (c < N3) {
            float a4 = 0.0f;
#pragma unroll 5
            for (int m = 0; m < N2; m += 4) {
                const float4 sv  = *(const float4*)&s3buf[g][m];
                const float4 wv4 = *(const float4*)&W3s[c * N2 + m];
                a4 = fmaf(sv.x, wv4.x, a4);
                a4 = fmaf(sv.y, wv4.y, a4);
                a4 = fmaf(sv.z, wv4.z, a4);
                a4 = fmaf(sv.w, wv4.w, a4);
            }
            const float h3 = swishf(a4);
            float mem4 = KV[0] * h3;
#pragma unroll
            for (int k = 0; k < 9; ++k) mem4 = fmaf(KV[k + 1], h3h[k], mem4);
#pragma unroll
            for (int k = 0; k < 9; ++k) mem4 = fmaf(-KS_TAIL[k], sl4h[k], mem4);
            const float s4 = sigm10(mem4 - 0.5f);
            accum += s4;
            out[b * N3 + c] = accum * 0.02f;
        }
    }
}

// ---------------------------------------------------------------------------
extern "C" void kernel_launch(void* const* d_in, const int* in_sizes, int n_in,
                              void* d_out, int out_size, void* d_ws, size_t ws_size,
                              hipStream_t stream) {
    const float* x  = (const float*)d_in[0];
    const float* W1 = (const float*)d_in[1];
    const float* W2 = (const float*)d_in[2];
    const float* W3 = (const float*)d_in[3];
    float* out = (float*)d_out;

    float* buf = (float*)d_ws;                                   // h1 -> syn2 in place
    unsigned short* W1pre  = (unsigned short*)(buf + (size_t)BATCH * T_STEPS * N1);
    unsigned short* W2pre2 = W1pre + 266240;

    prep_w1<<<1040, 256, 0, stream>>>(W1, W1pre);
    prep_w2<<<224, 256, 0, stream>>>(W2, W2pre2);
    gemm1_mfma<<<(BATCH * T_STEPS) / 128, 512, 0, stream>>>(x, W1pre, buf);
    conv_k<<<BATCH, 256, 0, stream>>>(buf);
    snn_scan3<<<BATCH / 16, 512, 0, stream>>>(buf, W2pre2, W3, out);
}

// Round 6
// 646.339 us; speedup vs baseline: 1.4479x; 1.4479x over previous
//
#include <hip/hip_runtime.h>
#include <math.h>

#define T_STEPS 50
#define D_IN    620
#define N1      200
#define N2      100
#define N3      11
#define BATCH   4096

typedef short bf16x8 __attribute__((ext_vector_type(8)));
typedef float f32x4  __attribute__((ext_vector_type(4)));

__device__ __constant__ float KV[10] = {
    -0.0033689735f, -0.0091578194f, -0.0248935342f, -0.0676676416f, -0.1839397206f,
     1.0f,           0.6065306597f,  0.3678794412f,  0.2231301601f,  0.1353352832f };
__device__ __constant__ float KS_TAIL[9] = {
    0.6065306597f, 0.3678794412f, 0.2231301601f, 0.1353352832f, 0.0820849986f,
    0.0497870684f, 0.0301973834f, 0.0183156389f, 0.0111089965f };

__device__ __forceinline__ float sigm10(float x) { return 1.0f / (1.0f + __expf(-10.0f * x)); }
__device__ __forceinline__ float swishf(float v) { return v / (1.0f + __expf(-10.0f * v)); }

__device__ __forceinline__ void split2(float x, unsigned short& hi, unsigned short& lo) {
    unsigned u = __float_as_uint(x);
    hi = (unsigned short)(u >> 16);
    float rem = x - __uint_as_float(u & 0xFFFF0000u);   // exact
    lo = (unsigned short)(__float_as_uint(rem) >> 16);
}

// ---------------------------------------------------------------------------
// Prep W1 -> 20 k-tiles of [p][208 rows][32 bf16], granule^=( (n>>1)&3 ).
// ---------------------------------------------------------------------------
__global__ void prep_w1(const float* __restrict__ W1, unsigned short* __restrict__ W1pre) {
    int i = blockIdx.x * 256 + threadIdx.x;           // 20*2*208*32 = 266240
    if (i >= 266240) return;
    int kk = i & 31;
    int t1 = i >> 5;
    int n  = t1 % 208;
    int t2 = t1 / 208;        // kt*2 + p
    int p  = t2 & 1;
    int kt = t2 >> 1;
    int k  = kt * 32 + kk;
    float w = (n < N1 && k < D_IN) ? W1[n * D_IN + k] : 0.0f;
    unsigned short hi, lo; split2(w, hi, lo);
    int gsw = (kk >> 3) ^ ((n >> 1) & 3);
    int idx = kt * 13312 + p * 6656 + n * 32 + gsw * 8 + (kk & 7);
    W1pre[idx] = p ? lo : hi;
}

// ---------------------------------------------------------------------------
// Prep W2 -> per-wave MFMA B-fragments (8 waves x 7 k-slices x {hi,lo})
// ---------------------------------------------------------------------------
__global__ void prep_w2(const float* __restrict__ W2, unsigned short* __restrict__ W2pre2) {
    int i = blockIdx.x * 256 + threadIdx.x;
    if (i >= 57344) return;
    int e  = i & 7;
    int r  = i >> 3;
    int l  = r & 63;
    int r2 = r >> 6;
    int p  = r2 & 1;
    int r3 = r2 >> 1;
    int ks = r3 % 7;
    int wv = r3 / 7;
    int n  = wv * 16 + (l & 15);
    int k  = ks * 32 + (l >> 4) * 8 + e;
    float v = (n < N2 && k < N1) ? W2[n * N1 + k] : 0.0f;
    unsigned short hi, lo; split2(v, hi, lo);
    W2pre2[i] = p ? lo : hi;
}

// ---------------------------------------------------------------------------
// MFMA GEMM1 v2 (unchanged): BM=128, BN=208, BK=32, 3-pass bf16.
// ---------------------------------------------------------------------------
__global__ __launch_bounds__(512, 4) void gemm1_mfma(const float* __restrict__ x,
                                                     const unsigned short* __restrict__ W1pre,
                                                     float* __restrict__ h1) {
    __shared__ unsigned short Bs[2][13312];           // 53248 B

    const int tid = threadIdx.x;
    const int w   = tid >> 6;
    const int l   = tid & 63;
    const int j   = l >> 4;
    const int r16 = l & 15;
    const long row0 = (long)blockIdx.x * 128;
    const float* arow = x + (row0 + w * 16 + r16) * D_IN;

    f32x4 acc[13];
#pragma unroll
    for (int nt = 0; nt < 13; ++nt) acc[nt] = (f32x4){0.f, 0.f, 0.f, 0.f};

    auto stageB = [&](int kt, int bb) {
        const unsigned short* src = W1pre + kt * 13312;
#pragma unroll
        for (int it = 0; it < 3; ++it) {
            int ch = it * 512 + tid;
            __builtin_amdgcn_global_load_lds(
                (const __attribute__((address_space(1))) unsigned int*)(src + ch * 8),
                (__attribute__((address_space(3))) unsigned int*)(&Bs[bb][0] + ch * 8), 16, 0, 0);
        }
        if (tid < 128) {
            int ch = 1536 + tid;
            __builtin_amdgcn_global_load_lds(
                (const __attribute__((address_space(1))) unsigned int*)(src + ch * 8),
                (__attribute__((address_space(3))) unsigned int*)(&Bs[bb][0] + ch * 8), 16, 0, 0);
        }
    };

    auto loadA = [&](int kt, float* av) {
        const float* p = arow + kt * 32 + j * 8;
        const float4 u0 = *(const float4*)p;
        const float4 u1 = *(const float4*)(p + 4);
        av[0] = u0.x; av[1] = u0.y; av[2] = u0.z; av[3] = u0.w;
        av[4] = u1.x; av[5] = u1.y; av[6] = u1.z; av[7] = u1.w;
    };
    auto loadAtail = [&](float* av) {
        if (j == 0) {
            const float4 u0 = *(const float4*)(arow + 608);
            const float4 u1 = *(const float4*)(arow + 612);
            av[0] = u0.x; av[1] = u0.y; av[2] = u0.z; av[3] = u0.w;
            av[4] = u1.x; av[5] = u1.y; av[6] = u1.z; av[7] = u1.w;
        } else if (j == 1) {
            const float4 u0 = *(const float4*)(arow + 616);
            av[0] = u0.x; av[1] = u0.y; av[2] = u0.z; av[3] = u0.w;
            av[4] = 0.f; av[5] = 0.f; av[6] = 0.f; av[7] = 0.f;
        } else {
#pragma unroll
            for (int e = 0; e < 8; ++e) av[e] = 0.f;
        }
    };

    float avc[8], avn[8];
    stageB(0, 0);
    loadA(0, avc);
    __syncthreads();

    for (int kt = 0; kt < 20; ++kt) {
        const int cur = kt & 1, nxt = cur ^ 1;
        if (kt < 19) {
            stageB(kt + 1, nxt);
            if (kt + 1 == 19) loadAtail(avn); else loadA(kt + 1, avn);
        }
        bf16x8 ah, al;
#pragma unroll
        for (int e = 0; e < 8; ++e) {
            unsigned short hi, lo; split2(avc[e], hi, lo);
            ah[e] = (short)hi; al[e] = (short)lo;
        }
        const unsigned short* B = &Bs[cur][0];
#pragma unroll
        for (int nt = 0; nt < 13; ++nt) {
            const int n  = nt * 16 + r16;
            const int gs = j ^ ((n >> 1) & 3);
            const bf16x8 bh = *(const bf16x8*)(B + n * 32 + gs * 8);
            const bf16x8 bl = *(const bf16x8*)(B + 6656 + n * 32 + gs * 8);
            acc[nt] = __builtin_amdgcn_mfma_f32_16x16x32_bf16(ah, bh, acc[nt], 0, 0, 0);
            acc[nt] = __builtin_amdgcn_mfma_f32_16x16x32_bf16(ah, bl, acc[nt], 0, 0, 0);
            acc[nt] = __builtin_amdgcn_mfma_f32_16x16x32_bf16(al, bh, acc[nt], 0, 0, 0);
        }
        __syncthreads();
#pragma unroll
        for (int e = 0; e < 8; ++e) avc[e] = avn[e];
    }

#pragma unroll
    for (int nt = 0; nt < 13; ++nt) {
        const int gcol = nt * 16 + r16;
        if (gcol < N1) {
            const long grow0 = row0 + w * 16 + j * 4;
#pragma unroll
            for (int q = 0; q < 4; ++q)
                h1[(grow0 + q) * N1 + gcol] = swishf(acc[nt][q]);
        }
    }
}

// ---------------------------------------------------------------------------
// In-place causal conv (unchanged)
// ---------------------------------------------------------------------------
__global__ __launch_bounds__(256) void conv_k(float* __restrict__ buf) {
    __shared__ float h1s[T_STEPS * N1];
    const int b = blockIdx.x, tid = threadIdx.x;
    float* p = buf + (size_t)b * (T_STEPS * N1);
    for (int i = tid; i < T_STEPS * N1 / 4; i += 256)
        ((float4*)h1s)[i] = ((const float4*)p)[i];
    __syncthreads();
    for (int i = tid; i < T_STEPS * N1; i += 256) {
        int t = i / N1, n = i - t * N1;
        float s = 0.0f;
#pragma unroll
        for (int k = 0; k < 10; ++k)
            if (k <= t) s = fmaf(KV[k], h1s[(t - k) * N1 + n], s);
        p[i] = s;
    }
}

// ---------------------------------------------------------------------------
// Recurrent scan v4: 8 elems/block, 512 threads, wave == elem.
// Per-thread state ~200 VGPR (NO spill). 2 barriers/step; P3-P5 wave-local.
// MFMA GEMM2: M=16 tile, rows 8..15 permanently zero.
// ---------------------------------------------------------------------------
__global__ __launch_bounds__(512, 2) void snn_scan4(const float* __restrict__ syn2,
                                                    const unsigned short* __restrict__ W2pre2,
                                                    const float* __restrict__ W3,
                                                    float* __restrict__ out) {
    __shared__ __align__(16) unsigned short s2A[8192];   // [p][16][256]; rows 8..15 stay 0
    __shared__ __align__(16) float h2buf[8][132];
    __shared__ __align__(16) float s3buf[8][104];
    __shared__ __align__(16) float W3s[N3 * N2];

    const int tid = threadIdx.x;
    const int wv  = tid >> 6;          // wave = elem (P1/P3/P5) and N-tile (P2)
    const int l   = tid & 63;
    const int m16 = l & 15;
    const int j2  = l >> 4;
    const int g   = wv;                // elem index in block
    const int c   = l;                 // lane within elem
    const long b  = (long)blockIdx.x * 8 + g;

    for (int i = tid; i < N3 * N2; i += 512) W3s[i] = W3[i];
    for (int i = tid; i < 8192; i += 512) s2A[i] = 0;

    // W2 B-fragments in registers (56 VGPR), loaded once
    bf16x8 bh[7], bl[7];
    {
        const unsigned short* wp = W2pre2 + wv * 7168 + l * 8;
#pragma unroll
        for (int ks = 0; ks < 7; ++ks) {
            bh[ks] = *(const bf16x8*)(wp + ks * 1024);
            bl[ks] = *(const bf16x8*)(wp + ks * 1024 + 512);
        }
    }

    const int NL2 = (c < 8)  ? 4 : 3;  // layer-2 ch n = c + 64j, n<200
    const int NL3 = (c < 36) ? 2 : 1;  // layer-3 ch m = c + 64j, m<100

    float sl2h[9][4] = {};
    float h2h[9][2]  = {};
    float sl3h[9][2] = {};
    float h3h[9]     = {};
    float sl4h[9]    = {};
    float accum      = 0.0f;

    const float* syn2b = syn2 + b * (T_STEPS * N1);
    float syn_nxt[4];
#pragma unroll
    for (int j = 0; j < 4; ++j) syn_nxt[j] = (j < NL2) ? syn2b[c + 64 * j] : 0.0f;

    __syncthreads();

    for (int t = 0; t < T_STEPS; ++t) {
        float syn_cur[4];
#pragma unroll
        for (int j = 0; j < 4; ++j) syn_cur[j] = syn_nxt[j];
        if (t + 1 < T_STEPS) {
#pragma unroll
            for (int j = 0; j < 4; ++j)
                if (j < NL2) syn_nxt[j] = syn2b[(t + 1) * N1 + c + 64 * j];
        }

        // ---- P1: layer-2 update -> s2A (rows 0..7) ----
#pragma unroll
        for (int j = 0; j < 4; ++j) {
            if (j < NL2) {
                const int n = c + 64 * j;
                float mem2 = syn_cur[j];
#pragma unroll
                for (int k = 0; k < 9; ++k) mem2 = fmaf(-KS_TAIL[k], sl2h[k][j], mem2);
                const float s2  = sigm10(mem2 - 0.5f);
                const float sl2 = s2 * mem2;
#pragma unroll
                for (int k = 8; k > 0; --k) sl2h[k][j] = sl2h[k - 1][j];
                sl2h[0][j] = sl2;
                unsigned short hi, lo; split2(s2, hi, lo);
                const int off = g * 256 + (((n >> 3) ^ (g & 7)) * 8) + (n & 7);
                s2A[off]        = hi;
                s2A[4096 + off] = lo;
            }
        }
        __syncthreads();                               // bar 1

        // ---- P2: MFMA GEMM2 (wave wv = N-tile; 2 independent chains) ----
        {
            f32x4 a0 = (f32x4){0.f, 0.f, 0.f, 0.f};
            f32x4 a1 = (f32x4){0.f, 0.f, 0.f, 0.f};
            const int swz = m16 & 7;
#pragma unroll
            for (int ks = 0; ks < 7; ++ks) {
                const int gr = (4 * ks + j2) ^ swz;
                const bf16x8 ahv = *(const bf16x8*)&s2A[m16 * 256 + gr * 8];
                const bf16x8 alv = *(const bf16x8*)&s2A[4096 + m16 * 256 + gr * 8];
                if (ks & 1) {
                    a1 = __builtin_amdgcn_mfma_f32_16x16x32_bf16(ahv, bh[ks], a1, 0, 0, 0);
                    a1 = __builtin_amdgcn_mfma_f32_16x16x32_bf16(alv, bh[ks], a1, 0, 0, 0);
                    a1 = __builtin_amdgcn_mfma_f32_16x16x32_bf16(ahv, bl[ks], a1, 0, 0, 0);
                } else {
                    a0 = __builtin_amdgcn_mfma_f32_16x16x32_bf16(ahv, bh[ks], a0, 0, 0, 0);
                    a0 = __builtin_amdgcn_mfma_f32_16x16x32_bf16(alv, bh[ks], a0, 0, 0, 0);
                    a0 = __builtin_amdgcn_mfma_f32_16x16x32_bf16(ahv, bl[ks], a0, 0, 0, 0);
                }
            }
            const f32x4 a = a0 + a1;
            if (j2 < 2) {                              // D rows 0..7 only
#pragma unroll
                for (int q = 0; q < 4; ++q)
                    h2buf[j2 * 4 + q][wv * 16 + m16] = swishf(a[q]);
            }
        }
        __syncthreads();                               // bar 2

        // ---- P3: layer-3 update (wave-local: reads h2buf[g]) ----
#pragma unroll
        for (int j = 0; j < 2; ++j) {
            if (j < NL3) {
                const int m = c + 64 * j;
                const float hm = h2buf[g][m];
                float mem3 = KV[0] * hm;
#pragma unroll
                for (int k = 0; k < 9; ++k) mem3 = fmaf(KV[k + 1], h2h[k][j], mem3);
#pragma unroll
                for (int k = 0; k < 9; ++k) mem3 = fmaf(-KS_TAIL[k], sl3h[k][j], mem3);
                const float s3  = sigm10(mem3 - 0.5f);
                const float sl3 = s3 * mem3;
#pragma unroll
                for (int k = 8; k > 0; --k) { h2h[k][j] = h2h[k - 1][j]; sl3h[k][j] = sl3h[k - 1][j]; }
                h2h[0][j]  = hm;
                sl3h[0][j] = sl3;
                s3buf[g][m] = s3;
            }
        }
        // same-wave DS visibility for s3buf before P4 reads
        asm volatile("s_waitcnt lgkmcnt(0)" ::: "memory");
        __builtin_amdgcn_sched_barrier(0);

        // ---- P4 + P5: GEMM3 + layer-4 (owner lanes c<11, wave-local) ----
        if (c < N3) {
            float a4 = 0.0f;
#pragma unroll 5
            for (int m = 0; m < N2; m += 4) {
                const float4 sv  = *(const float4*)&s3buf[g][m];
                const float4 wv4 = *(const float4*)&W3s[c * N2 + m];
                a4 = fmaf(sv.x, wv4.x, a4);
                a4 = fmaf(sv.y, wv4.y, a4);
                a4 = fmaf(sv.z, wv4.z, a4);
                a4 = fmaf(sv.w, wv4.w, a4);
            }
            const float h3 = swishf(a4);
            float mem4 = KV[0] * h3;
#pragma unroll
            for (int k = 0; k < 9; ++k) mem4 = fmaf(KV[k + 1], h3h[k], mem4);
#pragma unroll
            for (int k = 0; k < 9; ++k) mem4 = fmaf(-KS_TAIL[k], sl4h[k], mem4);
            const float s4  = sigm10(mem4 - 0.5f);
            const float sl4 = s4 * mem4;
#pragma unroll
            for (int k = 8; k > 0; --k) { h3h[k] = h3h[k - 1]; sl4h[k] = sl4h[k - 1]; }
            h3h[0]  = h3;
            sl4h[0] = sl4;
            accum += s4;
        }
    }

    if (c < N3) out[b * N3 + c] = accum * 0.02f;
}

// ---------------------------------------------------------------------------
extern "C" void kernel_launch(void* const* d_in, const int* in_sizes, int n_in,
                              void* d_out, int out_size, void* d_ws, size_t ws_size,
                              hipStream_t stream) {
    const float* x  = (const float*)d_in[0];
    const float* W1 = (const float*)d_in[1];
    const float* W2 = (const float*)d_in[2];
    const float* W3 = (const float*)d_in[3];
    float* out = (float*)d_out;

    float* buf = (float*)d_ws;                                   // h1 -> syn2 in place
    unsigned short* W1pre  = (unsigned short*)(buf + (size_t)BATCH * T_STEPS * N1);
    unsigned short* W2pre2 = W1pre + 266240;

    prep_w1<<<1040, 256, 0, stream>>>(W1, W1pre);
    prep_w2<<<224, 256, 0, stream>>>(W2, W2pre2);
    gemm1_mfma<<<(BATCH * T_STEPS) / 128, 512, 0, stream>>>(x, W1pre, buf);
    conv_k<<<BATCH, 256, 0, stream>>>(buf);
    snn_scan4<<<BATCH / 8, 512, 0, stream>>>(buf, W2pre2, W3, out);
}

// Round 7
// 582.393 us; speedup vs baseline: 1.6069x; 1.1098x over previous
//
#include <hip/hip_runtime.h>
#include <math.h>

#define T_STEPS 50
#define D_IN    620
#define N1      200
#define N2      100
#define N3      11
#define BATCH   4096

typedef short bf16x8 __attribute__((ext_vector_type(8)));
typedef float f32x4  __attribute__((ext_vector_type(4)));

__device__ __constant__ float KV[10] = {
    -0.0033689735f, -0.0091578194f, -0.0248935342f, -0.0676676416f, -0.1839397206f,
     1.0f,           0.6065306597f,  0.3678794412f,  0.2231301601f,  0.1353352832f };

#define RHO    0.60653066f     /* e^-1/2 */
#define RHO5   0.0820849986f   /* e^-5/2 */
#define RHO10  0.0067379470f   /* e^-5   */
#define KV0    (-0.0033689735f)
#define C1     (-0.0091578194f)
#define C2     (-0.0248935342f)
#define C3     (-0.0676676416f)
#define C4     (-0.1839397206f)

__device__ __forceinline__ float sigm10(float x) { return 1.0f / (1.0f + __expf(-10.0f * x)); }
__device__ __forceinline__ float swishf(float v) { return v / (1.0f + __expf(-10.0f * v)); }

__device__ __forceinline__ void split2(float x, unsigned short& hi, unsigned short& lo) {
    unsigned u = __float_as_uint(x);
    hi = (unsigned short)(u >> 16);
    float rem = x - __uint_as_float(u & 0xFFFF0000u);   // exact
    lo = (unsigned short)(__float_as_uint(rem) >> 16);
}

// ---------------------------------------------------------------------------
// Prep W1: 20 k-tiles x 2 n-halves x {hi,lo} x [112 rows][32 bf16],
// granule^=( (r>>1)&3 ).  Half-tile = 7168 ushorts = gemm LDS image.
// ---------------------------------------------------------------------------
__global__ void prep_w1(const float* __restrict__ W1, unsigned short* __restrict__ W1pre) {
    int i = blockIdx.x * 256 + threadIdx.x;           // 20*2*2*112*32 = 286720
    if (i >= 286720) return;
    int kk = i & 31;
    int t1 = i >> 5;
    int r  = t1 % 112;
    int t2 = t1 / 112;        // kt*4 + nb*2 + p
    int p  = t2 & 1;
    int nb = (t2 >> 1) & 1;
    int kt = t2 >> 2;
    int n  = nb * 112 + r;
    int k  = kt * 32 + kk;
    float w = (n < N1 && k < D_IN) ? W1[n * D_IN + k] : 0.0f;
    unsigned short hi, lo; split2(w, hi, lo);
    int gsw = (kk >> 3) ^ ((r >> 1) & 3);
    int idx = kt * 14336 + nb * 7168 + p * 3584 + r * 32 + gsw * 8 + (kk & 7);
    W1pre[idx] = p ? lo : hi;
}

// ---------------------------------------------------------------------------
// Prep W2 -> per-wave MFMA B-fragments (unchanged)
// ---------------------------------------------------------------------------
__global__ void prep_w2(const float* __restrict__ W2, unsigned short* __restrict__ W2pre2) {
    int i = blockIdx.x * 256 + threadIdx.x;
    if (i >= 57344) return;
    int e  = i & 7;
    int r  = i >> 3;
    int l  = r & 63;
    int r2 = r >> 6;
    int p  = r2 & 1;
    int r3 = r2 >> 1;
    int ks = r3 % 7;
    int wv = r3 / 7;
    int n  = wv * 16 + (l & 15);
    int k  = ks * 32 + (l >> 4) * 8 + e;
    float v = (n < N2 && k < N1) ? W2[n * N1 + k] : 0.0f;
    unsigned short hi, lo; split2(v, hi, lo);
    W2pre2[i] = p ? lo : hi;
}

// ---------------------------------------------------------------------------
// MFMA GEMM1 v4: BM=128 x BN=112, 4 waves (M=32/wave), BK=32, 3-pass bf16.
// Grid = (M/128) x 2 N-halves.  A: global->reg prefetch.  B: LDS dbuf 28.7KB.
// ---------------------------------------------------------------------------
__global__ __launch_bounds__(256, 4) void gemm1_mfma(const float* __restrict__ x,
                                                     const unsigned short* __restrict__ W1pre,
                                                     float* __restrict__ h1) {
    __shared__ unsigned short Bs[2][7168];            // 28672 B

    const int tid = threadIdx.x;
    const int w   = tid >> 6;          // wave 0..3
    const int l   = tid & 63;
    const int j   = l >> 4;
    const int r16 = l & 15;
    const int mb  = blockIdx.x >> 1;
    const int nb  = blockIdx.x & 1;
    const long row0 = (long)mb * 128;
    const float* arow0 = x + (row0 + w * 32 + r16) * D_IN;
    const float* arow1 = arow0 + 16 * D_IN;

    f32x4 acc[2][7];
#pragma unroll
    for (int mt = 0; mt < 2; ++mt)
#pragma unroll
        for (int nt = 0; nt < 7; ++nt) acc[mt][nt] = (f32x4){0.f, 0.f, 0.f, 0.f};

    auto stageB = [&](int kt, int bb) {
        const unsigned short* src = W1pre + kt * 14336 + nb * 7168;
#pragma unroll
        for (int it = 0; it < 3; ++it) {
            int ch = it * 256 + tid;                  // 16B chunks, 896 total
            __builtin_amdgcn_global_load_lds(
                (const __attribute__((address_space(1))) unsigned int*)(src + ch * 8),
                (__attribute__((address_space(3))) unsigned int*)(&Bs[bb][0] + ch * 8), 16, 0, 0);
        }
        if (tid < 128) {
            int ch = 768 + tid;
            __builtin_amdgcn_global_load_lds(
                (const __attribute__((address_space(1))) unsigned int*)(src + ch * 8),
                (__attribute__((address_space(3))) unsigned int*)(&Bs[bb][0] + ch * 8), 16, 0, 0);
        }
    };

    auto loadA = [&](int kt, float (&av)[2][8]) {
#pragma unroll
        for (int mt = 0; mt < 2; ++mt) {
            const float* ar = mt ? arow1 : arow0;
            if (kt < 19) {
                const float* p = ar + kt * 32 + j * 8;
                const float4 u0 = *(const float4*)p;
                const float4 u1 = *(const float4*)(p + 4);
                av[mt][0] = u0.x; av[mt][1] = u0.y; av[mt][2] = u0.z; av[mt][3] = u0.w;
                av[mt][4] = u1.x; av[mt][5] = u1.y; av[mt][6] = u1.z; av[mt][7] = u1.w;
            } else if (j == 0) {
                const float4 u0 = *(const float4*)(ar + 608);
                const float4 u1 = *(const float4*)(ar + 612);
                av[mt][0] = u0.x; av[mt][1] = u0.y; av[mt][2] = u0.z; av[mt][3] = u0.w;
                av[mt][4] = u1.x; av[mt][5] = u1.y; av[mt][6] = u1.z; av[mt][7] = u1.w;
            } else if (j == 1) {
                const float4 u0 = *(const float4*)(ar + 616);
                av[mt][0] = u0.x; av[mt][1] = u0.y; av[mt][2] = u0.z; av[mt][3] = u0.w;
                av[mt][4] = 0.f; av[mt][5] = 0.f; av[mt][6] = 0.f; av[mt][7] = 0.f;
            } else {
#pragma unroll
                for (int e = 0; e < 8; ++e) av[mt][e] = 0.f;
            }
        }
    };

    auto computeKt = [&](float (&av)[2][8], int cur) {
        bf16x8 ah[2], al[2];
#pragma unroll
        for (int mt = 0; mt < 2; ++mt)
#pragma unroll
            for (int e = 0; e < 8; ++e) {
                unsigned short hi, lo; split2(av[mt][e], hi, lo);
                ah[mt][e] = (short)hi; al[mt][e] = (short)lo;
            }
        const unsigned short* B = &Bs[cur][0];
#pragma unroll
        for (int nt = 0; nt < 7; ++nt) {
            const int n  = nt * 16 + r16;
            const int gs = j ^ ((n >> 1) & 3);
            const bf16x8 bh = *(const bf16x8*)(B + n * 32 + gs * 8);
            const bf16x8 bl = *(const bf16x8*)(B + 3584 + n * 32 + gs * 8);
            acc[0][nt] = __builtin_amdgcn_mfma_f32_16x16x32_bf16(ah[0], bh, acc[0][nt], 0, 0, 0);
            acc[1][nt] = __builtin_amdgcn_mfma_f32_16x16x32_bf16(ah[1], bh, acc[1][nt], 0, 0, 0);
            acc[0][nt] = __builtin_amdgcn_mfma_f32_16x16x32_bf16(ah[0], bl, acc[0][nt], 0, 0, 0);
            acc[1][nt] = __builtin_amdgcn_mfma_f32_16x16x32_bf16(ah[1], bl, acc[1][nt], 0, 0, 0);
            acc[0][nt] = __builtin_amdgcn_mfma_f32_16x16x32_bf16(al[0], bh, acc[0][nt], 0, 0, 0);
            acc[1][nt] = __builtin_amdgcn_mfma_f32_16x16x32_bf16(al[1], bh, acc[1][nt], 0, 0, 0);
        }
    };

    float avA[2][8], avB[2][8];
    stageB(0, 0);
    loadA(0, avA);
    __syncthreads();

#pragma unroll 1
    for (int kt = 0; kt < 20; kt += 2) {
        stageB(kt + 1, 1);
        loadA(kt + 1, avB);
        computeKt(avA, 0);
        __syncthreads();
        if (kt + 2 < 20) { stageB(kt + 2, 0); loadA(kt + 2, avA); }
        computeKt(avB, 1);
        __syncthreads();
    }

#pragma unroll
    for (int mt = 0; mt < 2; ++mt) {
        const long grow0 = row0 + w * 32 + mt * 16 + j * 4;
#pragma unroll
        for (int nt = 0; nt < 7; ++nt) {
            const int gcol = nb * 112 + nt * 16 + r16;
            if (gcol < N1) {
#pragma unroll
                for (int q = 0; q < 4; ++q)
                    h1[(grow0 + q) * N1 + gcol] = swishf(acc[mt][nt][q]);
            }
        }
    }
}

// ---------------------------------------------------------------------------
// In-place causal conv (unchanged)
// ---------------------------------------------------------------------------
__global__ __launch_bounds__(256) void conv_k(float* __restrict__ buf) {
    __shared__ float h1s[T_STEPS * N1];
    const int b = blockIdx.x, tid = threadIdx.x;
    float* p = buf + (size_t)b * (T_STEPS * N1);
    for (int i = tid; i < T_STEPS * N1 / 4; i += 256)
        ((float4*)h1s)[i] = ((const float4*)p)[i];
    __syncthreads();
    for (int i = tid; i < T_STEPS * N1; i += 256) {
        int t = i / N1, n = i - t * N1;
        float s = 0.0f;
#pragma unroll
        for (int k = 0; k < 10; ++k)
            if (k <= t) s = fmaf(KV[k], h1s[(t - k) * N1 + n], s);
        p[i] = s;
    }
}

// ---------------------------------------------------------------------------
// Recurrent scan v5: 8 elems/block, wave==elem; 10-deep circular histories
// (t-loop unrolled x10, all static), exponential-recurrence convs, 44-lane
// GEMM3 with within-wave LDS partial reduce.  2 barriers/step.
// ---------------------------------------------------------------------------
__global__ __launch_bounds__(512, 2) void snn_scan5(const float* __restrict__ syn2,
                                                    const unsigned short* __restrict__ W2pre2,
                                                    const float* __restrict__ W3,
                                                    float* __restrict__ out) {
    __shared__ __align__(16) unsigned short s2A[8192];   // [p][16][256]; rows 8..15 stay 0
    __shared__ __align__(16) float h2buf[8][132];
    __shared__ __align__(16) float s3buf[8][104];
    __shared__ __align__(16) float W3s[N3 * N2];
    __shared__ __align__(16) float pbuf[8][4][12];

    const int tid = threadIdx.x;
    const int wv  = tid >> 6;          // wave = elem (P1/P3/P5), N-tile (P2)
    const int l   = tid & 63;
    const int m16 = l & 15;
    const int j2  = l >> 4;
    const int g   = wv;
    const int c   = l;
    const long b  = (long)blockIdx.x * 8 + g;

    for (int i = tid; i < N3 * N2; i += 512) W3s[i] = W3[i];
    for (int i = tid; i < 8192; i += 512) s2A[i] = 0;

    bf16x8 bh[7], bl[7];
    {
        const unsigned short* wp = W2pre2 + wv * 7168 + l * 8;
#pragma unroll
        for (int ks = 0; ks < 7; ++ks) {
            bh[ks] = *(const bf16x8*)(wp + ks * 1024);
            bl[ks] = *(const bf16x8*)(wp + ks * 1024 + 512);
        }
    }

    const int NL2 = (c < 8)  ? 4 : 3;     // layer-2 ch n = c + 64j
    const int NL3 = (c < 36) ? 2 : 1;     // layer-3 ch m = c + 64j
    const int o4  = c % 11;               // GEMM3 output (c<44)
    const int p4  = c / 11;               // GEMM3 k-chunk
    const int kbeg = (p4 == 0) ? 0 : (4 + 24 * p4);   // 0,28,52,76
    const int nf4  = (p4 == 0) ? 7 : 6;

    float sl2h[10][4] = {}; float Ssl2[4] = {};
    float h2h[10][2]  = {}; float Dd3[2]  = {};
    float sl3h[10][2] = {}; float Ssl3[2] = {};
    float h3h[10]     = {}; float Dd4 = 0.f;
    float sl4h[10]    = {}; float Ssl4 = 0.f;
    float accum       = 0.0f;

    const float* syn2b = syn2 + b * (T_STEPS * N1);
    float syn_nxt[4];
#pragma unroll
    for (int jj = 0; jj < 4; ++jj) syn_nxt[jj] = (jj < NL2) ? syn2b[c + 64 * jj] : 0.0f;

    __syncthreads();

#pragma unroll 1
    for (int tb = 0; tb < T_STEPS; tb += 10) {
#pragma unroll
        for (int u = 0; u < 10; ++u) {
            const int t   = tb + u;
            const int um1 = (u + 9) % 10;   // lag 1
            const int um2 = (u + 8) % 10;   // lag 2
            const int um3 = (u + 7) % 10;   // lag 3
            const int um4 = (u + 6) % 10;   // lag 4
            const int um5 = (u + 5) % 10;   // lag 5

            float syn_cur[4];
#pragma unroll
            for (int jj = 0; jj < 4; ++jj) syn_cur[jj] = syn_nxt[jj];
            if (t + 1 < T_STEPS) {
#pragma unroll
                for (int jj = 0; jj < 4; ++jj)
                    if (jj < NL2) syn_nxt[jj] = syn2b[(t + 1) * N1 + c + 64 * jj];
            }

            // ---- P1: layer-2 (exact KS recurrence) ----
#pragma unroll
            for (int jj = 0; jj < 4; ++jj) {
                if (jj < NL2) {
                    const int n = c + 64 * jj;
                    const float slp = sl2h[um1][jj];
                    const float slo = sl2h[u][jj];          // lag 10
                    Ssl2[jj] = RHO * (Ssl2[jj] + slp) - RHO10 * slo;
                    const float mem2 = syn_cur[jj] - Ssl2[jj];
                    const float s2   = sigm10(mem2 - 0.5f);
                    sl2h[u][jj] = s2 * mem2;
                    unsigned short hi, lo; split2(s2, hi, lo);
                    const int off = g * 256 + (((n >> 3) ^ (g & 7)) * 8) + (n & 7);
                    s2A[off]        = hi;
                    s2A[4096 + off] = lo;
                }
            }
            __syncthreads();                               // bar 1

            // ---- P2: MFMA GEMM2 ----
            {
                f32x4 a0 = (f32x4){0.f, 0.f, 0.f, 0.f};
                f32x4 a1 = (f32x4){0.f, 0.f, 0.f, 0.f};
                const int swz = m16 & 7;
#pragma unroll
                for (int ks = 0; ks < 7; ++ks) {
                    const int gr = (4 * ks + j2) ^ swz;
                    const bf16x8 ahv = *(const bf16x8*)&s2A[m16 * 256 + gr * 8];
                    const bf16x8 alv = *(const bf16x8*)&s2A[4096 + m16 * 256 + gr * 8];
                    if (ks & 1) {
                        a1 = __builtin_amdgcn_mfma_f32_16x16x32_bf16(ahv, bh[ks], a1, 0, 0, 0);
                        a1 = __builtin_amdgcn_mfma_f32_16x16x32_bf16(alv, bh[ks], a1, 0, 0, 0);
                        a1 = __builtin_amdgcn_mfma_f32_16x16x32_bf16(ahv, bl[ks], a1, 0, 0, 0);
                    } else {
                        a0 = __builtin_amdgcn_mfma_f32_16x16x32_bf16(ahv, bh[ks], a0, 0, 0, 0);
                        a0 = __builtin_amdgcn_mfma_f32_16x16x32_bf16(alv, bh[ks], a0, 0, 0, 0);
                        a0 = __builtin_amdgcn_mfma_f32_16x16x32_bf16(ahv, bl[ks], a0, 0, 0, 0);
                    }
                }
                const f32x4 a = a0 + a1;
                if (j2 < 2) {
#pragma unroll
                    for (int q = 0; q < 4; ++q)
                        h2buf[j2 * 4 + q][wv * 16 + m16] = swishf(a[q]);
                }
            }
            __syncthreads();                               // bar 2

            // ---- P3: layer-3 (4-tap direct + exact decay recurrences) ----
#pragma unroll
            for (int jj = 0; jj < 2; ++jj) {
                if (jj < NL3) {
                    const int m = c + 64 * jj;
                    const float hm = h2buf[g][m];
                    float gneg = C1 * h2h[um1][jj];
                    gneg = fmaf(C2, h2h[um2][jj], gneg);
                    gneg = fmaf(C3, h2h[um3][jj], gneg);
                    gneg = fmaf(C4, h2h[um4][jj], gneg);
                    Dd3[jj] = fmaf(RHO, Dd3[jj], h2h[um5][jj]);
                    Dd3[jj] = fmaf(-RHO5, h2h[u][jj], Dd3[jj]);
                    const float slp = sl3h[um1][jj];
                    const float slo = sl3h[u][jj];
                    Ssl3[jj] = RHO * (Ssl3[jj] + slp) - RHO10 * slo;
                    const float mem3 = fmaf(KV0, hm, gneg) + Dd3[jj] - Ssl3[jj];
                    const float s3   = sigm10(mem3 - 0.5f);
                    sl3h[u][jj] = s3 * mem3;
                    h2h[u][jj]  = hm;
                    s3buf[g][m] = s3;
                }
            }
            asm volatile("s_waitcnt lgkmcnt(0)" ::: "memory");
            __builtin_amdgcn_sched_barrier(0);

            // ---- P4: GEMM3 partials (44 lanes) ----
            if (c < 44) {
                float part = 0.0f;
#pragma unroll
                for (int i = 0; i < 7; ++i) {
                    if (i < nf4) {
                        const float4 sv  = *(const float4*)&s3buf[g][kbeg + 4 * i];
                        const float4 wv4 = *(const float4*)&W3s[o4 * N2 + kbeg + 4 * i];
                        part = fmaf(sv.x, wv4.x, part);
                        part = fmaf(sv.y, wv4.y, part);
                        part = fmaf(sv.z, wv4.z, part);
                        part = fmaf(sv.w, wv4.w, part);
                    }
                }
                pbuf[g][p4][o4] = part;
            }
            asm volatile("s_waitcnt lgkmcnt(0)" ::: "memory");
            __builtin_amdgcn_sched_barrier(0);

            // ---- P5: layer-4 (11 lanes) ----
            if (c < N3) {
                const float a4 = pbuf[g][0][c] + pbuf[g][1][c] + pbuf[g][2][c] + pbuf[g][3][c];
                const float h3 = swishf(a4);
                float gneg = C1 * h3h[um1];
                gneg = fmaf(C2, h3h[um2], gneg);
                gneg = fmaf(C3, h3h[um3], gneg);
                gneg = fmaf(C4, h3h[um4], gneg);
                Dd4 = fmaf(RHO, Dd4, h3h[um5]);
                Dd4 = fmaf(-RHO5, h3h[u], Dd4);
                const float slp = sl4h[um1];
                const float slo = sl4h[u];
                Ssl4 = RHO * (Ssl4 + slp) - RHO10 * slo;
                const float mem4 = fmaf(KV0, h3, gneg) + Dd4 - Ssl4;
                const float s4   = sigm10(mem4 - 0.5f);
                sl4h[u] = s4 * mem4;
                h3h[u]  = h3;
                accum += s4;
            }
        }
    }

    if (c < N3) out[b * N3 + c] = accum * 0.02f;
}

// ---------------------------------------------------------------------------
extern "C" void kernel_launch(void* const* d_in, const int* in_sizes, int n_in,
                              void* d_out, int out_size, void* d_ws, size_t ws_size,
                              hipStream_t stream) {
    const float* x  = (const float*)d_in[0];
    const float* W1 = (const float*)d_in[1];
    const float* W2 = (const float*)d_in[2];
    const float* W3 = (const float*)d_in[3];
    float* out = (float*)d_out;

    float* buf = (float*)d_ws;                                   // h1 -> syn2 in place
    unsigned short* W1pre  = (unsigned short*)(buf + (size_t)BATCH * T_STEPS * N1);
    unsigned short* W2pre2 = W1pre + 286720;

    prep_w1<<<1120, 256, 0, stream>>>(W1, W1pre);
    prep_w2<<<224, 256, 0, stream>>>(W2, W2pre2);
    gemm1_mfma<<<3200, 256, 0, stream>>>(x, W1pre, buf);
    conv_k<<<BATCH, 256, 0, stream>>>(buf);
    snn_scan5<<<BATCH / 8, 512, 0, stream>>>(buf, W2pre2, W3, out);
}

// Round 9
// 529.733 us; speedup vs baseline: 1.7666x; 1.0994x over previous
//
#include <hip/hip_runtime.h>
#include <math.h>

#define T_STEPS 50
#define D_IN    620
#define N1      200
#define N2      100
#define N3      11
#define BATCH   4096

typedef short bf16x8 __attribute__((ext_vector_type(8)));
typedef float f32x4  __attribute__((ext_vector_type(4)));

__device__ __constant__ float KV[10] = {
    -0.0033689735f, -0.0091578194f, -0.0248935342f, -0.0676676416f, -0.1839397206f,
     1.0f,           0.6065306597f,  0.3678794412f,  0.2231301601f,  0.1353352832f };

#define RHO    0.60653066f     /* e^-1/2 */
#define RHO5   0.0820849986f   /* e^-5/2 */
#define RHO10  0.0067379470f   /* e^-5   */
#define KV0    (-0.0033689735f)
#define C1     (-0.0091578194f)
#define C2     (-0.0248935342f)
#define C3     (-0.0676676416f)
#define C4     (-0.1839397206f)

__device__ __forceinline__ float sigm10(float x) { return 1.0f / (1.0f + __expf(-10.0f * x)); }
__device__ __forceinline__ float swishf(float v) { return v / (1.0f + __expf(-10.0f * v)); }

__device__ __forceinline__ void split2(float x, unsigned short& hi, unsigned short& lo) {
    unsigned u = __float_as_uint(x);
    hi = (unsigned short)(u >> 16);
    float rem = x - __uint_as_float(u & 0xFFFF0000u);   // exact
    lo = (unsigned short)(__float_as_uint(rem) >> 16);
}

// ---------------------------------------------------------------------------
// Prep W1 -> 20 k-tiles of [p][208 rows][32 bf16], granule^=( (n>>1)&3 ).
// Tile = 13312 ushorts (26624 B) = gemm1's LDS B image.
// ---------------------------------------------------------------------------
__global__ void prep_w1(const float* __restrict__ W1, unsigned short* __restrict__ W1pre) {
    int i = blockIdx.x * 256 + threadIdx.x;           // 20*2*208*32 = 266240
    if (i >= 266240) return;
    int kk = i & 31;
    int t1 = i >> 5;
    int n  = t1 % 208;
    int t2 = t1 / 208;        // kt*2 + p
    int p  = t2 & 1;
    int kt = t2 >> 1;
    int k  = kt * 32 + kk;
    float w = (n < N1 && k < D_IN) ? W1[n * D_IN + k] : 0.0f;
    unsigned short hi, lo; split2(w, hi, lo);
    int gsw = (kk >> 3) ^ ((n >> 1) & 3);
    int idx = kt * 13312 + p * 6656 + n * 32 + gsw * 8 + (kk & 7);
    W1pre[idx] = p ? lo : hi;
}

// ---------------------------------------------------------------------------
// Prep W2 -> per-wave MFMA B-fragments (unchanged)
// ---------------------------------------------------------------------------
__global__ void prep_w2(const float* __restrict__ W2, unsigned short* __restrict__ W2pre2) {
    int i = blockIdx.x * 256 + threadIdx.x;
    if (i >= 57344) return;
    int e  = i & 7;
    int r  = i >> 3;
    int l  = r & 63;
    int r2 = r >> 6;
    int p  = r2 & 1;
    int r3 = r2 >> 1;
    int ks = r3 % 7;
    int wv = r3 / 7;
    int n  = wv * 16 + (l & 15);
    int k  = ks * 32 + (l >> 4) * 8 + e;
    float v = (n < N2 && k < N1) ? W2[n * N1 + k] : 0.0f;
    unsigned short hi, lo; split2(v, hi, lo);
    W2pre2[i] = p ? lo : hi;
}

// ---------------------------------------------------------------------------
// MFMA GEMM1 v5b: BM=128 (8 waves x M=16), BN=208, BK=32, 3-pass bf16.
// x read ONCE per row. B: 3-buffer LDS (78KB), stageB 2 tiles ahead,
// counted-vmcnt barriers in steady state; FULL drain (vmcnt 0) at kt==18
// (fixes round-8 race: loadAtail's divergent branches issue 3 loads/wave,
// which shifted the queue so vmcnt(2) left 2 stageB(19) chunks in flight).
// ---------------------------------------------------------------------------
__global__ __launch_bounds__(512, 4) void gemm1_mfma(const float* __restrict__ x,
                                                     const unsigned short* __restrict__ W1pre,
                                                     float* __restrict__ h1) {
    __shared__ unsigned short Bs[3][13312];           // 79872 B -> 2 blocks/CU

    const int tid = threadIdx.x;
    const int w   = tid >> 6;
    const int l   = tid & 63;
    const int j   = l >> 4;
    const int r16 = l & 15;
    const long row0 = (long)blockIdx.x * 128;
    const float* arow = x + (row0 + w * 16 + r16) * D_IN;

    f32x4 acc[13];
#pragma unroll
    for (int nt = 0; nt < 13; ++nt) acc[nt] = (f32x4){0.f, 0.f, 0.f, 0.f};

    auto stageB = [&](int kt, int bb) {
        const unsigned short* src = W1pre + kt * 13312;
        unsigned short* dst = &Bs[bb][0];
#pragma unroll
        for (int it = 0; it < 3; ++it) {
            int ch = it * 512 + tid;                  // 16B chunk index
            __builtin_amdgcn_global_load_lds(
                (const __attribute__((address_space(1))) unsigned int*)(src + ch * 8),
                (__attribute__((address_space(3))) unsigned int*)(dst + ch * 8), 16, 0, 0);
        }
        if (tid < 128) {
            int ch = 1536 + tid;
            __builtin_amdgcn_global_load_lds(
                (const __attribute__((address_space(1))) unsigned int*)(src + ch * 8),
                (__attribute__((address_space(3))) unsigned int*)(dst + ch * 8), 16, 0, 0);
        }
    };

    auto loadA = [&](int kt, float* av) {
        const float* p = arow + kt * 32 + j * 8;
        const float4 u0 = *(const float4*)p;
        const float4 u1 = *(const float4*)(p + 4);
        av[0] = u0.x; av[1] = u0.y; av[2] = u0.z; av[3] = u0.w;
        av[4] = u1.x; av[5] = u1.y; av[6] = u1.z; av[7] = u1.w;
    };
    // kt=19 tail: cols 608..619 valid; never read past row end
    auto loadAtail = [&](float* av) {
        if (j == 0) {
            const float4 u0 = *(const float4*)(arow + 608);
            const float4 u1 = *(const float4*)(arow + 612);
            av[0] = u0.x; av[1] = u0.y; av[2] = u0.z; av[3] = u0.w;
            av[4] = u1.x; av[5] = u1.y; av[6] = u1.z; av[7] = u1.w;
        } else if (j == 1) {
            const float4 u0 = *(const float4*)(arow + 616);
            av[0] = u0.x; av[1] = u0.y; av[2] = u0.z; av[3] = u0.w;
            av[4] = 0.f; av[5] = 0.f; av[6] = 0.f; av[7] = 0.f;
        } else {
#pragma unroll
            for (int e = 0; e < 8; ++e) av[e] = 0.f;
        }
    };

    float av[2][8];
    // prologue: 2-deep prefetch
    stageB(0, 0);
    stageB(1, 1);
    loadA(0, av[0]);
    loadA(1, av[1]);
    // drain stageB(0) (oldest); keep stageB(1)+loadA(0..1) in flight
    asm volatile("s_waitcnt vmcnt(7)" ::: "memory");
    asm volatile("s_barrier" ::: "memory");

#pragma unroll 1
    for (int kt = 0; kt < 20; ++kt) {
        // split A(kt) into hi/lo bf16 fragments (consumes av[kt&1])
        bf16x8 ah, al;
#pragma unroll
        for (int e = 0; e < 8; ++e) {
            unsigned short hi, lo; split2(av[kt & 1][e], hi, lo);
            ah[e] = (short)hi; al[e] = (short)lo;
        }
        // issue prefetch for kt+2 (reuses av slot just consumed)
        if (kt < 18) {
            if (kt + 2 == 19) loadAtail(av[kt & 1]); else loadA(kt + 2, av[kt & 1]);
            stageB(kt + 2, (kt + 2) % 3);
        }
        const unsigned short* B = &Bs[kt % 3][0];
#pragma unroll
        for (int nt = 0; nt < 13; ++nt) {
            const int n  = nt * 16 + r16;
            const int gs = j ^ ((n >> 1) & 3);
            const bf16x8 bh = *(const bf16x8*)(B + n * 32 + gs * 8);
            const bf16x8 bl = *(const bf16x8*)(B + 6656 + n * 32 + gs * 8);
            acc[nt] = __builtin_amdgcn_mfma_f32_16x16x32_bf16(ah, bh, acc[nt], 0, 0, 0);
            acc[nt] = __builtin_amdgcn_mfma_f32_16x16x32_bf16(ah, bl, acc[nt], 0, 0, 0);
            acc[nt] = __builtin_amdgcn_mfma_f32_16x16x32_bf16(al, bh, acc[nt], 0, 0, 0);
        }
        // counted-vmcnt barrier: drain stageB(kt+1), keep stageB(kt+2)+loadA.
        // kt==18: FULL drain so Bs[1] (tile 19) is complete before last read.
        if (kt < 18) {
            asm volatile("s_waitcnt vmcnt(5)" ::: "memory");
            asm volatile("s_barrier" ::: "memory");
        } else if (kt == 18) {
            asm volatile("s_waitcnt vmcnt(0)" ::: "memory");
            asm volatile("s_barrier" ::: "memory");
        }
    }

    // epilogue: D row = w*16 + j*4+q, col = nt*16 + r16
#pragma unroll
    for (int nt = 0; nt < 13; ++nt) {
        const int gcol = nt * 16 + r16;
        if (gcol < N1) {
            const long grow0 = row0 + w * 16 + j * 4;
#pragma unroll
            for (int q = 0; q < 4; ++q)
                h1[(grow0 + q) * N1 + gcol] = swishf(acc[nt][q]);
        }
    }
}

// ---------------------------------------------------------------------------
// In-place causal conv (unchanged)
// ---------------------------------------------------------------------------
__global__ __launch_bounds__(256) void conv_k(float* __restrict__ buf) {
    __shared__ float h1s[T_STEPS * N1];
    const int b = blockIdx.x, tid = threadIdx.x;
    float* p = buf + (size_t)b * (T_STEPS * N1);
    for (int i = tid; i < T_STEPS * N1 / 4; i += 256)
        ((float4*)h1s)[i] = ((const float4*)p)[i];
    __syncthreads();
    for (int i = tid; i < T_STEPS * N1; i += 256) {
        int t = i / N1, n = i - t * N1;
        float s = 0.0f;
#pragma unroll
        for (int k = 0; k < 10; ++k)
            if (k <= t) s = fmaf(KV[k], h1s[(t - k) * N1 + n], s);
        p[i] = s;
    }
}

// ---------------------------------------------------------------------------
// Recurrent scan v5 (unchanged from round 7)
// ---------------------------------------------------------------------------
__global__ __launch_bounds__(512, 2) void snn_scan5(const float* __restrict__ syn2,
                                                    const unsigned short* __restrict__ W2pre2,
                                                    const float* __restrict__ W3,
                                                    float* __restrict__ out) {
    __shared__ __align__(16) unsigned short s2A[8192];   // [p][16][256]; rows 8..15 stay 0
    __shared__ __align__(16) float h2buf[8][132];
    __shared__ __align__(16) float s3buf[8][104];
    __shared__ __align__(16) float W3s[N3 * N2];
    __shared__ __align__(16) float pbuf[8][4][12];

    const int tid = threadIdx.x;
    const int wv  = tid >> 6;
    const int l   = tid & 63;
    const int m16 = l & 15;
    const int j2  = l >> 4;
    const int g   = wv;
    const int c   = l;
    const long b  = (long)blockIdx.x * 8 + g;

    for (int i = tid; i < N3 * N2; i += 512) W3s[i] = W3[i];
    for (int i = tid; i < 8192; i += 512) s2A[i] = 0;

    bf16x8 bh[7], bl[7];
    {
        const unsigned short* wp = W2pre2 + wv * 7168 + l * 8;
#pragma unroll
        for (int ks = 0; ks < 7; ++ks) {
            bh[ks] = *(const bf16x8*)(wp + ks * 1024);
            bl[ks] = *(const bf16x8*)(wp + ks * 1024 + 512);
        }
    }

    const int NL2 = (c < 8)  ? 4 : 3;
    const int NL3 = (c < 36) ? 2 : 1;
    const int o4  = c % 11;
    const int p4  = c / 11;
    const int kbeg = (p4 == 0) ? 0 : (4 + 24 * p4);
    const int nf4  = (p4 == 0) ? 7 : 6;

    float sl2h[10][4] = {}; float Ssl2[4] = {};
    float h2h[10][2]  = {}; float Dd3[2]  = {};
    float sl3h[10][2] = {}; float Ssl3[2] = {};
    float h3h[10]     = {}; float Dd4 = 0.f;
    float sl4h[10]    = {}; float Ssl4 = 0.f;
    float accum       = 0.0f;

    const float* syn2b = syn2 + b * (T_STEPS * N1);
    float syn_nxt[4];
#pragma unroll
    for (int jj = 0; jj < 4; ++jj) syn_nxt[jj] = (jj < NL2) ? syn2b[c + 64 * jj] : 0.0f;

    __syncthreads();

#pragma unroll 1
    for (int tb = 0; tb < T_STEPS; tb += 10) {
#pragma unroll
        for (int u = 0; u < 10; ++u) {
            const int t   = tb + u;
            const int um1 = (u + 9) % 10;
            const int um2 = (u + 8) % 10;
            const int um3 = (u + 7) % 10;
            const int um4 = (u + 6) % 10;
            const int um5 = (u + 5) % 10;

            float syn_cur[4];
#pragma unroll
            for (int jj = 0; jj < 4; ++jj) syn_cur[jj] = syn_nxt[jj];
            if (t + 1 < T_STEPS) {
#pragma unroll
                for (int jj = 0; jj < 4; ++jj)
                    if (jj < NL2) syn_nxt[jj] = syn2b[(t + 1) * N1 + c + 64 * jj];
            }

            // ---- P1: layer-2 (exact KS recurrence) ----
#pragma unroll
            for (int jj = 0; jj < 4; ++jj) {
                if (jj < NL2) {
                    const int n = c + 64 * jj;
                    const float slp = sl2h[um1][jj];
                    const float slo = sl2h[u][jj];          // lag 10
                    Ssl2[jj] = RHO * (Ssl2[jj] + slp) - RHO10 * slo;
                    const float mem2 = syn_cur[jj] - Ssl2[jj];
                    const float s2   = sigm10(mem2 - 0.5f);
                    sl2h[u][jj] = s2 * mem2;
                    unsigned short hi, lo; split2(s2, hi, lo);
                    const int off = g * 256 + (((n >> 3) ^ (g & 7)) * 8) + (n & 7);
                    s2A[off]        = hi;
                    s2A[4096 + off] = lo;
                }
            }
            __syncthreads();                               // bar 1

            // ---- P2: MFMA GEMM2 ----
            {
                f32x4 a0 = (f32x4){0.f, 0.f, 0.f, 0.f};
                f32x4 a1 = (f32x4){0.f, 0.f, 0.f, 0.f};
                const int swz = m16 & 7;
#pragma unroll
                for (int ks = 0; ks < 7; ++ks) {
                    const int gr = (4 * ks + j2) ^ swz;
                    const bf16x8 ahv = *(const bf16x8*)&s2A[m16 * 256 + gr * 8];
                    const bf16x8 alv = *(const bf16x8*)&s2A[4096 + m16 * 256 + gr * 8];
                    if (ks & 1) {
                        a1 = __builtin_amdgcn_mfma_f32_16x16x32_bf16(ahv, bh[ks], a1, 0, 0, 0);
                        a1 = __builtin_amdgcn_mfma_f32_16x16x32_bf16(alv, bh[ks], a1, 0, 0, 0);
                        a1 = __builtin_amdgcn_mfma_f32_16x16x32_bf16(ahv, bl[ks], a1, 0, 0, 0);
                    } else {
                        a0 = __builtin_amdgcn_mfma_f32_16x16x32_bf16(ahv, bh[ks], a0, 0, 0, 0);
                        a0 = __builtin_amdgcn_mfma_f32_16x16x32_bf16(alv, bh[ks], a0, 0, 0, 0);
                        a0 = __builtin_amdgcn_mfma_f32_16x16x32_bf16(ahv, bl[ks], a0, 0, 0, 0);
                    }
                }
                const f32x4 a = a0 + a1;
                if (j2 < 2) {
#pragma unroll
                    for (int q = 0; q < 4; ++q)
                        h2buf[j2 * 4 + q][wv * 16 + m16] = swishf(a[q]);
                }
            }
            __syncthreads();                               // bar 2

            // ---- P3: layer-3 ----
#pragma unroll
            for (int jj = 0; jj < 2; ++jj) {
                if (jj < NL3) {
                    const int m = c + 64 * jj;
                    const float hm = h2buf[g][m];
                    float gneg = C1 * h2h[um1][jj];
                    gneg = fmaf(C2, h2h[um2][jj], gneg);
                    gneg = fmaf(C3, h2h[um3][jj], gneg);
                    gneg = fmaf(C4, h2h[um4][jj], gneg);
                    Dd3[jj] = fmaf(RHO, Dd3[jj], h2h[um5][jj]);
                    Dd3[jj] = fmaf(-RHO5, h2h[u][jj], Dd3[jj]);
                    const float slp = sl3h[um1][jj];
                    const float slo = sl3h[u][jj];
                    Ssl3[jj] = RHO * (Ssl3[jj] + slp) - RHO10 * slo;
                    const float mem3 = fmaf(KV0, hm, gneg) + Dd3[jj] - Ssl3[jj];
                    const float s3   = sigm10(mem3 - 0.5f);
                    sl3h[u][jj] = s3 * mem3;
                    h2h[u][jj]  = hm;
                    s3buf[g][m] = s3;
                }
            }
            asm volatile("s_waitcnt lgkmcnt(0)" ::: "memory");
            __builtin_amdgcn_sched_barrier(0);

            // ---- P4: GEMM3 partials (44 lanes) ----
            if (c < 44) {
                float part = 0.0f;
#pragma unroll
                for (int i = 0; i < 7; ++i) {
                    if (i < nf4) {
                        const float4 sv  = *(const float4*)&s3buf[g][kbeg + 4 * i];
                        const float4 wv4 = *(const float4*)&W3s[o4 * N2 + kbeg + 4 * i];
                        part = fmaf(sv.x, wv4.x, part);
                        part = fmaf(sv.y, wv4.y, part);
                        part = fmaf(sv.z, wv4.z, part);
                        part = fmaf(sv.w, wv4.w, part);
                    }
                }
                pbuf[g][p4][o4] = part;
            }
            asm volatile("s_waitcnt lgkmcnt(0)" ::: "memory");
            __builtin_amdgcn_sched_barrier(0);

            // ---- P5: layer-4 (11 lanes) ----
            if (c < N3) {
                const float a4 = pbuf[g][0][c] + pbuf[g][1][c] + pbuf[g][2][c] + pbuf[g][3][c];
                const float h3 = swishf(a4);
                float gneg = C1 * h3h[um1];
                gneg = fmaf(C2, h3h[um2], gneg);
                gneg = fmaf(C3, h3h[um3], gneg);
                gneg = fmaf(C4, h3h[um4], gneg);
                Dd4 = fmaf(RHO, Dd4, h3h[um5]);
                Dd4 = fmaf(-RHO5, h3h[u], Dd4);
                const float slp = sl4h[um1];
                const float slo = sl4h[u];
                Ssl4 = RHO * (Ssl4 + slp) - RHO10 * slo;
                const float mem4 = fmaf(KV0, h3, gneg) + Dd4 - Ssl4;
                const float s4   = sigm10(mem4 - 0.5f);
                sl4h[u] = s4 * mem4;
                h3h[u]  = h3;
                accum += s4;
            }
        }
    }

    if (c < N3) out[b * N3 + c] = accum * 0.02f;
}

// ---------------------------------------------------------------------------
extern "C" void kernel_launch(void* const* d_in, const int* in_sizes, int n_in,
                              void* d_out, int out_size, void* d_ws, size_t ws_size,
                              hipStream_t stream) {
    const float* x  = (const float*)d_in[0];
    const float* W1 = (const float*)d_in[1];
    const float* W2 = (const float*)d_in[2];
    const float* W3 = (const float*)d_in[3];
    float* out = (float*)d_out;

    float* buf = (float*)d_ws;                                   // h1 -> syn2 in place
    unsigned short* W1pre  = (unsigned short*)(buf + (size_t)BATCH * T_STEPS * N1);
    unsigned short* W2pre2 = W1pre + 266240;

    prep_w1<<<1040, 256, 0, stream>>>(W1, W1pre);
    prep_w2<<<224, 256, 0, stream>>>(W2, W2pre2);
    gemm1_mfma<<<1600, 512, 0, stream>>>(x, W1pre, buf);
    conv_k<<<BATCH, 256, 0, stream>>>(buf);
    snn_scan5<<<BATCH / 8, 512, 0, stream>>>(buf, W2pre2, W3, out);
}